// Round 7
// baseline (511.038 us; speedup 1.0000x reference)
//
#include <hip/hip_runtime.h>
#include <math.h>

typedef unsigned short u16;
typedef __bf16 bf16x8 __attribute__((ext_vector_type(8)));
typedef float f32x4 __attribute__((ext_vector_type(4)));
typedef unsigned short u16x8 __attribute__((ext_vector_type(8)));
typedef unsigned short u16x4 __attribute__((ext_vector_type(4)));

#define H 2048
#define LSEQ 1024
#define LP (LSEQ+3)
#define CL 32
#define NCH 32

__device__ __forceinline__ float bf2f(u16 u) {
    union { float f; unsigned int i; } x; x.i = ((unsigned int)u) << 16; return x.f;
}
__device__ __forceinline__ u16 f2bf(float f) {
    union { float f; unsigned int i; } x; x.f = f;
    unsigned int r = x.i + 0x7fffu + ((x.i >> 16) & 1u);
    return (u16)(r >> 16);
}

__device__ __forceinline__ void gload_lds16(const void* g, void* l) {
    __builtin_amdgcn_global_load_lds((const __attribute__((address_space(1))) void*)g,
                                     (__attribute__((address_space(3))) void*)l,
                                     16, 0, 0);
}

enum { EPI_XZ = 0, EPI_DELTA = 1, EPI_STORE = 5, EPI_P2 = 6 };

// ---------------- 128x256 tile, 8-wave, 5-buffer counted-vmcnt GEMM ----------------
// 512 threads = 8 waves (2M x 4N), wave tile 64x64, BK=32, LDS 120 KB (1 block/CU).
// Depth-4 prefetch, steady-state s_waitcnt vmcnt(9); XCD panel swizzle.
// K-step split into 3 m201-style phases: {ds_reads [P0: + stage issue] -> s_barrier
// -> lgkmcnt(0) -> setprio(1) MFMA cluster setprio(0) -> s_barrier} so the LDS-read
// windows and MFMA windows alternate cleanly across all 8 waves and staging writes
// land under the MFMA windows. Counted vmcnt once per step (end of P2).
template<int EPI, bool APAD>
__launch_bounds__(512, 2)
__global__ void gemmA(const u16* __restrict__ A, const u16* __restrict__ B,
                      int lda, int ldb, long aZoff, long bZoff, int iters,
                      void* __restrict__ out0, void* __restrict__ out1,
                      void* __restrict__ out2, const float* __restrict__ aux) {
    __shared__ u16 As[5][128 * 32];
    __shared__ u16 Bs[5][256 * 32];
    // bijective remap (requires gridDim.x==16, gridDim.y*gridDim.z==16)
    const int flat = blockIdx.x + gridDim.x * (blockIdx.y + gridDim.y * blockIdx.z);
    const int xr = flat & 7;
    const int jj = flat >> 3;
    const int panel = xr + 8 * (jj >> 4);
    const int mI = jj & 15;
    const int m0 = mI * 128;
    const int yI = panel % gridDim.y;
    const int z  = panel / gridDim.y;
    const int n0 = yI * 256;
    const int tid = threadIdx.x;
    const int lane = tid & 63;
    const int w = tid >> 6;          // 0..7
    const int wr = w >> 2;           // 0..1 (M half, 64 rows)
    const int wc = w & 3;            // 0..3 (N quarter, 64 cols)

    long abase;
    if (APAD) {
        int b = m0 >> 10, l0 = m0 & 1023;
        abase = (long)(b * LP + l0) * lda;
    } else {
        abase = (long)m0 * lda;
    }
    const u16* Ag = A + abase + (long)z * aZoff;
    const u16* Bg = B + (long)n0 * ldb + (long)z * bZoff;

    const int sw8 = ((((lane & 15) >> 1) & 3) ^ (lane >> 4)) * 8;

    f32x4 acc[4][4];
#pragma unroll
    for (int i = 0; i < 4; i++)
#pragma unroll
        for (int j = 0; j < 4; j++) acc[i][j] = (f32x4){0.f, 0.f, 0.f, 0.f};

    // stage: A 512 granules (1/thread), B 1024 granules (2/thread) -> 3 loads/thread
#define STG(s, bi)                                                                \
    {                                                                             \
        const int k0_ = (s) * 32;                                                 \
        {                                                                         \
            const int rA_ = tid >> 2;                                             \
            const int sgA_ = ((tid & 3) ^ ((rA_ >> 1) & 3)) * 8;                  \
            gload_lds16(Ag + (long)rA_ * lda + k0_ + sgA_, &As[bi][tid * 8]);     \
        }                                                                         \
        _Pragma("unroll")                                                         \
        for (int l_ = 0; l_ < 2; l_++) {                                          \
            const int idx_ = l_ * 512 + tid;                                      \
            const int rB_ = idx_ >> 2;                                            \
            const int sgB_ = ((idx_ & 3) ^ ((rB_ >> 1) & 3)) * 8;                 \
            gload_lds16(Bg + (long)rB_ * ldb + k0_ + sgB_, &Bs[bi][idx_ * 8]);    \
        }                                                                         \
    }

#define LDA_F(i) (*(const bf16x8*)&As[cur][(wr * 64 + (i) * 16 + (lane & 15)) * 32 + sw8])
#define LDB_F(j) (*(const bf16x8*)&Bs[cur][(wc * 64 + (j) * 16 + (lane & 15)) * 32 + sw8])
#define MFMA(i, j, a, b) acc[i][j] = __builtin_amdgcn_mfma_f32_16x16x32_bf16((a), (b), acc[i][j], 0, 0, 0)

    // prologue: stage up to 4 K-steps ahead
    STG(0, 0);
    if (iters > 1) STG(1, 1);
    if (iters > 2) STG(2, 2);
    if (iters > 3) STG(3, 3);
    {
        const int pre = iters < 4 ? iters : 4;
        if      (pre == 4) asm volatile("s_waitcnt vmcnt(9)" ::: "memory");
        else if (pre == 3) asm volatile("s_waitcnt vmcnt(6)" ::: "memory");
        else if (pre == 2) asm volatile("s_waitcnt vmcnt(3)" ::: "memory");
        else               asm volatile("s_waitcnt vmcnt(0)" ::: "memory");
    }
    __builtin_amdgcn_s_barrier();
    __builtin_amdgcn_sched_barrier(0);

    int cur = 0;
    for (int t = 0; t < iters; ++t) {
        const int sb = cur ? cur - 1 : 4;   // buffer for stage t+4 (= buffer read at t-1)
        bf16x8 a0, a1, a2, a3, b0, b1, b2, b3;

        // ---- phase 0: 4 ds_reads + stage issue -> 4 MFMA ----
        a0 = LDA_F(0); a1 = LDA_F(1); b0 = LDB_F(0); b1 = LDB_F(1);
        if (t + 4 < iters) STG(t + 4, sb);
        __builtin_amdgcn_sched_barrier(0);
        __builtin_amdgcn_s_barrier();
        asm volatile("s_waitcnt lgkmcnt(0)" ::: "memory");
        __builtin_amdgcn_sched_barrier(0);
        __builtin_amdgcn_s_setprio(1);
        MFMA(0, 0, a0, b0); MFMA(0, 1, a0, b1);
        MFMA(1, 0, a1, b0); MFMA(1, 1, a1, b1);
        __builtin_amdgcn_s_setprio(0);
        __builtin_amdgcn_sched_barrier(0);
        __builtin_amdgcn_s_barrier();

        // ---- phase 1: 2 ds_reads -> 4 MFMA ----
        b2 = LDB_F(2); b3 = LDB_F(3);
        __builtin_amdgcn_sched_barrier(0);
        __builtin_amdgcn_s_barrier();
        asm volatile("s_waitcnt lgkmcnt(0)" ::: "memory");
        __builtin_amdgcn_sched_barrier(0);
        __builtin_amdgcn_s_setprio(1);
        MFMA(0, 2, a0, b2); MFMA(0, 3, a0, b3);
        MFMA(1, 2, a1, b2); MFMA(1, 3, a1, b3);
        __builtin_amdgcn_s_setprio(0);
        __builtin_amdgcn_sched_barrier(0);
        __builtin_amdgcn_s_barrier();

        // ---- phase 2: 2 ds_reads -> 8 MFMA, counted vmcnt, step barrier ----
        a2 = LDA_F(2); a3 = LDA_F(3);
        __builtin_amdgcn_sched_barrier(0);
        __builtin_amdgcn_s_barrier();
        asm volatile("s_waitcnt lgkmcnt(0)" ::: "memory");
        __builtin_amdgcn_sched_barrier(0);
        __builtin_amdgcn_s_setprio(1);
        MFMA(2, 0, a2, b0); MFMA(2, 1, a2, b1);
        MFMA(3, 0, a3, b0); MFMA(3, 1, a3, b1);
        MFMA(2, 2, a2, b2); MFMA(2, 3, a2, b3);
        MFMA(3, 2, a3, b2); MFMA(3, 3, a3, b3);
        __builtin_amdgcn_s_setprio(0);
        __builtin_amdgcn_sched_barrier(0);
        if (t < iters - 1) {
            const int lastst = (t + 4 < iters - 1) ? t + 4 : iters - 1;
            const int ahead = lastst - (t + 1);   // stages allowed to stay in flight
            if      (ahead >= 3) asm volatile("s_waitcnt vmcnt(9)" ::: "memory");
            else if (ahead == 2) asm volatile("s_waitcnt vmcnt(6)" ::: "memory");
            else if (ahead == 1) asm volatile("s_waitcnt vmcnt(3)" ::: "memory");
            else                 asm volatile("s_waitcnt vmcnt(0)" ::: "memory");
            __builtin_amdgcn_s_barrier();
            __builtin_amdgcn_sched_barrier(0);
        }
        cur = (cur == 4) ? 0 : cur + 1;
    }
#undef STG
#undef LDA_F
#undef LDB_F
#undef MFMA

#pragma unroll
    for (int i = 0; i < 4; i++) {
#pragma unroll
        for (int j = 0; j < 4; j++) {
#pragma unroll
            for (int r = 0; r < 4; r++) {
                const int m = m0 + wr * 64 + i * 16 + ((lane >> 4) << 2) + r;
                const int n = n0 + wc * 64 + j * 16 + (lane & 15);
                float v = acc[i][j][r];
                if constexpr (EPI == EPI_XZ) {
                    const int b = m >> 10, l = m & 1023;
                    if (n < H) ((u16*)out0)[((long)(b * LP + l + 3)) * H + n] = f2bf(v);
                    else       ((u16*)out1)[(long)m * H + (n - H)] = f2bf(v);
                } else {  // EPI_P2: fp32 split-K partial stores
                    if (z == 0) {
                        ((float*)out0)[(long)m * H + n] = v;
                    } else {
                        float* p = (m < 1024) ? (float*)out1 : (float*)out2;
                        p[(long)(m & 1023) * H + n] = v;
                    }
                }
            }
        }
    }
}

// ---------------- 128x128 tile GEMM, 2-barrier (DELTA only) ----------------
template<int EPI, bool APAD>
__launch_bounds__(256)
__global__ void gemm_bt(const u16* __restrict__ A, const u16* __restrict__ B,
                        int K, long aZoff, long bZoff, int itersZ, int ldc,
                        void* __restrict__ out0, void* __restrict__ out1,
                        const float* __restrict__ bias) {
    __shared__ u16 As[128 * 32];
    __shared__ u16 Bs[128 * 32];
    const int m0 = blockIdx.x * 128;
    const int n0 = blockIdx.y * 128;
    const int z  = blockIdx.z;
    const int tid = threadIdx.x;
    const int lane = tid & 63;
    const int w = tid >> 6;
    const int wr = w >> 1, wc = w & 1;

    long abase = (long)m0 * K;
    const u16* Ag = A + abase + (long)z * aZoff;
    const u16* Bg = B + (long)n0 * K + (long)z * bZoff;

    const int sw8 = ((((lane & 15) >> 1) & 3) ^ (lane >> 4)) * 8;

    f32x4 acc[4][4];
#pragma unroll
    for (int i = 0; i < 4; i++)
#pragma unroll
        for (int j = 0; j < 4; j++) acc[i][j] = (f32x4){0.f, 0.f, 0.f, 0.f};

    for (int kt = 0; kt < itersZ; ++kt) {
        const int k0 = kt * 32;
        __syncthreads();
#pragma unroll
        for (int j = 0; j < 2; j++) {
            const int idx = j * 256 + tid;
            const int r = idx >> 2;
            const int segG = ((idx & 3) ^ ((r >> 1) & 3)) * 8;
            gload_lds16(Ag + (long)r * K + k0 + segG, &As[idx * 8]);
            gload_lds16(Bg + (long)r * K + k0 + segG, &Bs[idx * 8]);
        }
        __syncthreads();
        bf16x8 af[4], bfr[4];
#pragma unroll
        for (int i = 0; i < 4; i++) {
            const int row = wr * 64 + i * 16 + (lane & 15);
            af[i] = *(const bf16x8*)&As[row * 32 + sw8];
        }
#pragma unroll
        for (int j = 0; j < 4; j++) {
            const int row = wc * 64 + j * 16 + (lane & 15);
            bfr[j] = *(const bf16x8*)&Bs[row * 32 + sw8];
        }
#pragma unroll
        for (int i = 0; i < 4; i++)
#pragma unroll
            for (int j = 0; j < 4; j++)
                acc[i][j] = __builtin_amdgcn_mfma_f32_16x16x32_bf16(af[i], bfr[j], acc[i][j], 0, 0, 0);
    }

#pragma unroll
    for (int i = 0; i < 4; i++) {
#pragma unroll
        for (int j = 0; j < 4; j++) {
#pragma unroll
            for (int r = 0; r < 4; r++) {
                const int m = m0 + wr * 64 + i * 16 + ((lane >> 4) << 2) + r;
                const int n = n0 + wc * 64 + j * 16 + (lane & 15);
                float v = acc[i][j][r];
                if constexpr (EPI == EPI_DELTA) {
                    v += bias[n];
                    v = (v > 20.f) ? v : log1pf(expf(v));   // softplus
                    ((float*)out0)[(long)m * H + n] = v;
                }
            }
        }
    }
}

// ---------------- 128x128 deep-pipelined GEMM (dBC only, proven) ----------
template<int EPI, bool APAD>
__launch_bounds__(256)
__global__ void gemm128d(const u16* __restrict__ A, const u16* __restrict__ B,
                         int lda, int ldb, int iters,
                         long aZoff, long bZoff, long oZoff, int ldo,
                         void* __restrict__ out0, void* __restrict__ out1,
                         const float* __restrict__ aux) {
    __shared__ u16 As[6][128 * 32];
    __shared__ u16 Bs[6][128 * 32];
    const int m0 = blockIdx.y * 128;
    const int n0 = blockIdx.x * 128;
    const int z  = blockIdx.z;
    const int tid = threadIdx.x;
    const int lane = tid & 63;
    const int w = tid >> 6;
    const int wr = w >> 1, wc = w & 1;

    long abase = (long)m0 * lda;
    const u16* Ag = A + abase + (long)z * aZoff;
    const u16* Bg = B + (long)n0 * ldb + (long)z * bZoff;

    const int sw8 = ((((lane & 15) >> 1) & 3) ^ (lane >> 4)) * 8;

    f32x4 acc[4][4];
#pragma unroll
    for (int i = 0; i < 4; i++)
#pragma unroll
        for (int j = 0; j < 4; j++) acc[i][j] = (f32x4){0.f, 0.f, 0.f, 0.f};

#define STG(s, bi)                                                                \
    {                                                                             \
        const int k0_ = (s) * 32;                                                 \
        _Pragma("unroll")                                                         \
        for (int l_ = 0; l_ < 2; l_++) {                                          \
            const int idx_ = l_ * 256 + tid;                                      \
            const int r_ = idx_ >> 2;                                             \
            const int segG_ = ((idx_ & 3) ^ ((r_ >> 1) & 3)) * 8;                 \
            gload_lds16(Ag + (long)r_ * lda + k0_ + segG_, &As[bi][idx_ * 8]);    \
            gload_lds16(Bg + (long)r_ * ldb + k0_ + segG_, &Bs[bi][idx_ * 8]);    \
        }                                                                         \
    }

    STG(0, 0);
    if (iters > 1) STG(1, 1);
    if (iters > 2) STG(2, 2);
    if (iters > 3) STG(3, 3);
    if (iters > 4) STG(4, 4);
    {
        const int pre = iters < 5 ? iters : 5;
        if      (pre == 5) asm volatile("s_waitcnt vmcnt(16)" ::: "memory");
        else if (pre == 4) asm volatile("s_waitcnt vmcnt(12)" ::: "memory");
        else if (pre == 3) asm volatile("s_waitcnt vmcnt(8)" ::: "memory");
        else if (pre == 2) asm volatile("s_waitcnt vmcnt(4)" ::: "memory");
        else               asm volatile("s_waitcnt vmcnt(0)" ::: "memory");
    }
    __builtin_amdgcn_s_barrier();
    __builtin_amdgcn_sched_barrier(0);

    int cur = 0;
    for (int t = 0; t < iters; ++t) {
        const int sb = cur ? cur - 1 : 5;
        if (t + 5 < iters) STG(t + 5, sb);

        bf16x8 af[4], bfr[4];
#pragma unroll
        for (int i = 0; i < 4; i++) {
            const int row = wr * 64 + i * 16 + (lane & 15);
            af[i] = *(const bf16x8*)&As[cur][row * 32 + sw8];
        }
#pragma unroll
        for (int j = 0; j < 4; j++) {
            const int row = wc * 64 + j * 16 + (lane & 15);
            bfr[j] = *(const bf16x8*)&Bs[cur][row * 32 + sw8];
        }
        __builtin_amdgcn_s_setprio(1);
#pragma unroll
        for (int i = 0; i < 4; i++)
#pragma unroll
            for (int j = 0; j < 4; j++)
                acc[i][j] = __builtin_amdgcn_mfma_f32_16x16x32_bf16(af[i], bfr[j], acc[i][j], 0, 0, 0);
        __builtin_amdgcn_s_setprio(0);

        if (t < iters - 1) {
            const int lastst = (t + 5 < iters - 1) ? t + 5 : iters - 1;
            const int ahead = lastst - (t + 1);
            if      (ahead >= 4) asm volatile("s_waitcnt vmcnt(16)" ::: "memory");
            else if (ahead == 3) asm volatile("s_waitcnt vmcnt(12)" ::: "memory");
            else if (ahead == 2) asm volatile("s_waitcnt vmcnt(8)" ::: "memory");
            else if (ahead == 1) asm volatile("s_waitcnt vmcnt(4)" ::: "memory");
            else                 asm volatile("s_waitcnt vmcnt(0)" ::: "memory");
            __builtin_amdgcn_s_barrier();
            __builtin_amdgcn_sched_barrier(0);
        }
        cur = (cur == 5) ? 0 : cur + 1;
    }
#undef STG

#pragma unroll
    for (int i = 0; i < 4; i++) {
#pragma unroll
        for (int j = 0; j < 4; j++) {
#pragma unroll
            for (int r = 0; r < 4; r++) {
                const int m = m0 + wr * 64 + i * 16 + ((lane >> 4) << 2) + r;
                const int n = n0 + wc * 64 + j * 16 + (lane & 15);
                float v = acc[i][j][r];
                if constexpr (EPI == EPI_STORE) {
                    ((float*)out0 + (long)z * oZoff)[(long)m * ldo + n] = v;
                }
            }
        }
    }
}

// conv finalize: sum fp32 partials (p0 full; p1 m-split) + bias + silu -> bf16 xcc
__global__ void fin_conv2(const float* __restrict__ p0, const float* __restrict__ p1a,
                          const float* __restrict__ p1b, const float* __restrict__ bias,
                          u16* __restrict__ xcc) {
    const long i = ((long)blockIdx.x * 256 + threadIdx.x) * 4;
    f32x4 a = *(const f32x4*)(p0 + i);
    const long half = (long)1024 * 2048;
    const float* p1 = (i < half) ? p1a : p1b;
    const long i1 = (i < half) ? i : i - half;
    f32x4 b = *(const f32x4*)(p1 + i1);
    const int n = (int)(i & 2047);
    f32x4 bv = *(const f32x4*)(bias + n);
    u16x4 o;
#pragma unroll
    for (int j = 0; j < 4; j++) {
        float t = a[j] + b[j] + bv[j];
        o[j] = f2bf(t / (1.f + expf(-t)));
    }
    *(u16x4*)(xcc + i) = o;
}

// out finalize: sum fp32 partials + residual x -> fp32 out
__global__ void fin_out2(const float* __restrict__ p0, const float* __restrict__ p1a,
                         const float* __restrict__ p1b, const float* __restrict__ x,
                         float* __restrict__ out) {
    const long i = ((long)blockIdx.x * 256 + threadIdx.x) * 4;
    f32x4 a = *(const f32x4*)(p0 + i);
    const long half = (long)1024 * 2048;
    const float* p1 = (i < half) ? p1a : p1b;
    const long i1 = (i < half) ? i : i - half;
    f32x4 b = *(const f32x4*)(p1 + i1);
    f32x4 xv = *(const f32x4*)(x + i);
    f32x4 v;
#pragma unroll
    for (int j = 0; j < 4; j++) v[j] = xv[j] + a[j] + b[j];
    *(f32x4*)(out + i) = v;
}

// dbc finalize: sum 8 fp32 partials (T x 128) -> dbc fp32 (T x 96) + dbc64 bf16 (T x 64)
__global__ void fin_dbc_k(const float* __restrict__ pacc, float* __restrict__ dbc,
                          u16* __restrict__ dbc64) {
    const int i = blockIdx.x * 256 + threadIdx.x;
    const int m = i >> 7, n = i & 127;
    float v = 0.f;
#pragma unroll
    for (int zz = 0; zz < 8; zz++) v += pacc[zz * 262144 + i];
    if (n < 96) dbc[m * 96 + n] = v;
    if (n < 64) dbc64[m * 64 + n] = f2bf(v);
}

// conv_w (tap,i,o) fp32 -> Wt (o, tap*H+i) bf16  (fused-tap layout, ldb = 4*H)
__global__ void transpose_w(const float* __restrict__ in, u16* __restrict__ out) {
    __shared__ u16 s[64][72];
    const int tap = blockIdx.z;
    const long base = (long)tap * H * H;
    const int i0 = blockIdx.x * 64, o0 = blockIdx.y * 64;
    const int r = threadIdx.x >> 3;
    const int c = (threadIdx.x & 7) * 8;
#pragma unroll
    for (int rr = r; rr < 64; rr += 32) {
        f32x4 a = *(const f32x4*)&in[base + (long)(i0 + rr) * H + o0 + c];
        f32x4 b = *(const f32x4*)&in[base + (long)(i0 + rr) * H + o0 + c + 4];
#pragma unroll
        for (int j = 0; j < 4; j++) { s[rr][c + j] = f2bf(a[j]); s[rr][c + 4 + j] = f2bf(b[j]); }
    }
    __syncthreads();
#pragma unroll
    for (int rr = r; rr < 64; rr += 32) {
        u16x8 v;
#pragma unroll
        for (int j = 0; j < 8; j++) v[j] = s[c + j][rr];
        *(u16x8*)&out[(long)(o0 + rr) * (4 * H) + (long)tap * H + i0 + c] = v;
    }
}

__global__ void cast_f2b_k(const float* __restrict__ in, u16* __restrict__ out) {
    const long i = ((long)blockIdx.x * 256 + threadIdx.x) * 4;
    f32x4 v = *(const f32x4*)(in + i);
    u16x4 o;
#pragma unroll
    for (int j = 0; j < 4; j++) o[j] = f2bf(v[j]);
    *(u16x4*)(out + i) = o;
}

__global__ void pad_zero_k(u16* __restrict__ xcp) {
    const int i = blockIdx.x * 256 + threadIdx.x;
    const int b = i / (3 * H);
    const int r = i - b * 3 * H;
    xcp[(long)b * LP * H + r] = 0;
}

__global__ void xpw_k(const float* __restrict__ xp, u16* __restrict__ out) {
    const int i = blockIdx.x * 256 + threadIdx.x;
    const int r = i >> 11;
    out[i] = (r < 96) ? f2bf(xp[i]) : (u16)0;
}

__global__ void rmsnorm_k(const float* __restrict__ x, const float* __restrict__ w, u16* __restrict__ h) {
    const long base = (long)blockIdx.x * H;
    const int tid = threadIdx.x;
    f32x4 a = *(const f32x4*)&x[base + tid * 8];
    f32x4 b = *(const f32x4*)&x[base + tid * 8 + 4];
    float f[8];
    float ss = 0.f;
#pragma unroll
    for (int j = 0; j < 4; j++) { f[j] = a[j]; f[4 + j] = b[j]; }
#pragma unroll
    for (int j = 0; j < 8; j++) ss += f[j] * f[j];
#pragma unroll
    for (int m = 32; m > 0; m >>= 1) ss += __shfl_down(ss, m);
    __shared__ float red[4];
    if ((tid & 63) == 0) red[tid >> 6] = ss;
    __syncthreads();
    ss = red[0] + red[1] + red[2] + red[3];
    const float scale = rsqrtf(ss * (1.f / H) + 1e-5f);
    f32x4 wa = *(const f32x4*)&w[tid * 8];
    f32x4 wb = *(const f32x4*)&w[tid * 8 + 4];
    u16x8 o;
#pragma unroll
    for (int j = 0; j < 4; j++) { o[j] = f2bf(f[j] * scale * wa[j]); o[4 + j] = f2bf(f[4 + j] * scale * wb[j]); }
    *(u16x8*)&h[base + tid * 8] = o;
}

// ---------- chunked scan, channel-per-thread ----------
__launch_bounds__(256)
__global__ void scan_part1(const float* __restrict__ delta, const u16* __restrict__ xc,
                           const float* __restrict__ dbc, const float* __restrict__ alog,
                           u16* __restrict__ ssum, float* __restrict__ sdl_buf) {
    __shared__ float sB[CL * 16];
    const int tid = threadIdx.x;
    const int bc = blockIdx.x;
    const int b = bc >> 5, c = bc & 31;
    const int h = blockIdx.y * 256 + tid;
    const long tok0 = (long)b * LSEQ + c * CL;
    {
        const int r = tid >> 4, n = tid & 15;
        sB[tid] = dbc[(tok0 + r) * 96 + 64 + n];
        sB[tid + 256] = dbc[(tok0 + r + 16) * 96 + 64 + n];
    }
    __syncthreads();
    float An[16]; bool fast = true;
#pragma unroll
    for (int n = 0; n < 16; n++) {
        An[n] = -expf(alog[h * 16 + n]);
        fast = fast && (fabsf(An[n] + (float)(n + 1)) < 1e-3f * (n + 1));
    }
    float s[16];
#pragma unroll
    for (int n = 0; n < 16; n++) s[n] = 0.f;
    float sdl = 0.f;
    const float* dptr = delta + tok0 * H + h;
    const u16* xptr = xc + tok0 * H + h;
    float dl = dptr[0], xv = bf2f(xptr[0]);
    if (fast) {
        for (int j = 0; j < CL; j++) {
            const long jn = (j < CL - 1) ? (long)(j + 1) * H : (long)j * H;
            const float dl2 = dptr[jn]; const float xv2 = bf2f(xptr[jn]);
            sdl += dl;
            const float e1 = expf(-dl);
            const float u = dl * xv;
            const f32x4* Bv = (const f32x4*)&sB[j * 16];
            float ep = 1.f;
#pragma unroll
            for (int q = 0; q < 4; q++) {
                const f32x4 bb = Bv[q];
#pragma unroll
                for (int k = 0; k < 4; k++) { ep *= e1; s[q*4+k] = ep * s[q*4+k] + u * bb[k]; }
            }
            dl = dl2; xv = xv2;
        }
    } else {
        for (int j = 0; j < CL; j++) {
            const long jn = (j < CL - 1) ? (long)(j + 1) * H : (long)j * H;
            const float dl2 = dptr[jn]; const float xv2 = bf2f(xptr[jn]);
            sdl += dl;
            const float u = dl * xv;
            const f32x4* Bv = (const f32x4*)&sB[j * 16];
#pragma unroll
            for (int q = 0; q < 4; q++) {
                const f32x4 bb = Bv[q];
#pragma unroll
                for (int k = 0; k < 4; k++) { const float e = expf(dl * An[q*4+k]); s[q*4+k] = e * s[q*4+k] + u * bb[k]; }
            }
            dl = dl2; xv = xv2;
        }
    }
    u16x8 o0, o1;
#pragma unroll
    for (int n = 0; n < 8; n++) { o0[n] = f2bf(s[n]); o1[n] = f2bf(s[8 + n]); }
    const long sb = ((long)bc * H + h) * 16;
    *(u16x8*)&ssum[sb] = o0;
    *(u16x8*)&ssum[sb + 8] = o1;
    sdl_buf[(long)bc * H + h] = sdl;
}

__global__ void scan_mid(u16* __restrict__ ssum, const float* __restrict__ sdl_buf,
                         const float* __restrict__ alog) {
    const int tg = blockIdx.x * 256 + threadIdx.x;
    const int b = tg >> 15;
    const int rest = tg & 32767;
    const int h = rest >> 4, n = rest & 15;
    const float An = -expf(alog[h * 16 + n]);
    float S = 0.f;
    for (int c = 0; c < NCH; c++) {
        const long base = (long)(b * NCH + c) * H + h;
        const float a = expf(An * sdl_buf[base]);
        const long si = base * 16 + n;
        const float sloc = bf2f(ssum[si]);
        ssum[si] = f2bf(S);
        S = a * S + sloc;
    }
}

__launch_bounds__(256)
__global__ void scan_part3(const float* __restrict__ delta, const u16* __restrict__ xc,
                           const float* __restrict__ dbc, const float* __restrict__ alog,
                           const float* __restrict__ dvec, const u16* __restrict__ z,
                           const u16* __restrict__ ssum, u16* __restrict__ ybuf) {
    __shared__ float sB[CL * 16];
    __shared__ float sC[CL * 16];
    const int tid = threadIdx.x;
    const int bc = blockIdx.x;
    const int b = bc >> 5, c = bc & 31;
    const int h = blockIdx.y * 256 + tid;
    const long tok0 = (long)b * LSEQ + c * CL;
    {
        const int r = tid >> 4, n = tid & 15;
        sB[tid]       = dbc[(tok0 + r) * 96 + 64 + n];
        sB[tid + 256] = dbc[(tok0 + r + 16) * 96 + 64 + n];
        sC[tid]       = dbc[(tok0 + r) * 96 + 80 + n];
        sC[tid + 256] = dbc[(tok0 + r + 16) * 96 + 80 + n];
    }
    __syncthreads();
    float An[16]; bool fast = true;
#pragma unroll
    for (int n = 0; n < 16; n++) {
        An[n] = -expf(alog[h * 16 + n]);
        fast = fast && (fabsf(An[n] + (float)(n + 1)) < 1e-3f * (n + 1));
    }
    float s[16];
    {
        const long sb = ((long)bc * H + h) * 16;
        u16x8 i0 = *(const u16x8*)&ssum[sb];
        u16x8 i1 = *(const u16x8*)&ssum[sb + 8];
#pragma unroll
        for (int n = 0; n < 8; n++) { s[n] = bf2f(i0[n]); s[8 + n] = bf2f(i1[n]); }
    }
    const float Dh = dvec[h];
    const float* dptr = delta + tok0 * H + h;
    const u16* xptr = xc + tok0 * H + h;
    const u16* zptr = z + tok0 * H + h;
    u16* yptr = ybuf + tok0 * H + h;
    float dl = dptr[0], xv = bf2f(xptr[0]), zf = bf2f(zptr[0]);
    if (fast) {
        for (int j = 0; j < CL; j++) {
            const long jn = (j < CL - 1) ? (long)(j + 1) * H : (long)j * H;
            const float dl2 = dptr[jn]; const float xv2 = bf2f(xptr[jn]); const float zf2 = bf2f(zptr[jn]);
            const float e1 = expf(-dl);
            const float u = dl * xv;
            const f32x4* Bv = (const f32x4*)&sB[j * 16];
            const f32x4* Cv = (const f32x4*)&sC[j * 16];
            float ep = 1.f, y = 0.f;
#pragma unroll
            for (int q = 0; q < 4; q++) {
                const f32x4 bb = Bv[q], cc = Cv[q];
#pragma unroll
                for (int k = 0; k < 4; k++) {
                    ep *= e1;
                    s[q*4+k] = ep * s[q*4+k] + u * bb[k];
                    y += s[q*4+k] * cc[k];
                }
            }
            y += Dh * xv;
            const float g = zf / (1.f + expf(-zf));
            yptr[(long)j * H] = f2bf(y * g);
            dl = dl2; xv = xv2; zf = zf2;
        }
    } else {
        for (int j = 0; j < CL; j++) {
            const long jn = (j < CL - 1) ? (long)(j + 1) * H : (long)j * H;
            const float dl2 = dptr[jn]; const float xv2 = bf2f(xptr[jn]); const float zf2 = bf2f(zptr[jn]);
            const float u = dl * xv;
            const f32x4* Bv = (const f32x4*)&sB[j * 16];
            const f32x4* Cv = (const f32x4*)&sC[j * 16];
            float y = 0.f;
#pragma unroll
            for (int q = 0; q < 4; q++) {
                const f32x4 bb = Bv[q], cc = Cv[q];
#pragma unroll
                for (int k = 0; k < 4; k++) {
                    const float e = expf(dl * An[q*4+k]);
                    s[q*4+k] = e * s[q*4+k] + u * bb[k];
                    y += s[q*4+k] * cc[k];
                }
            }
            y += Dh * xv;
            const float g = zf / (1.f + expf(-zf));
            yptr[(long)j * H] = f2bf(y * g);
            dl = dl2; xv = xv2; zf = zf2;
        }
    }
}

extern "C" void kernel_launch(void* const* d_in, const int* in_sizes, int n_in,
                              void* d_out, int out_size, void* d_ws, size_t ws_size,
                              hipStream_t stream) {
    const float* x       = (const float*)d_in[0];
    const float* norm_w  = (const float*)d_in[1];
    const float* in_proj = (const float*)d_in[2];
    const float* conv_w  = (const float*)d_in[3];
    const float* conv_b  = (const float*)d_in[4];
    const float* x_proj  = (const float*)d_in[5];
    const float* dt_w    = (const float*)d_in[6];
    const float* dt_b    = (const float*)d_in[7];
    const float* a_log   = (const float*)d_in[8];
    const float* Dv      = (const float*)d_in[9];
    const float* out_w   = (const float*)d_in[10];
    float* out = (float*)d_out;

    char* ws = (char*)d_ws;
    // region roles over time (total 86,138,880 bytes):
    u16*   xcp    = (u16*)(ws);                   //  8,413,184  XZ pad-xc -> conv A -> xcc -> out partial p1b (fp32 half)
    u16*   hy     = (u16*)(ws + 8413184);         //  8,388,608  h -> conv partial p1a (fp32 half) -> out partial p1a
    float* hyF    = (float*)(ws + 8413184);
    u16*   z_buf  = (u16*)(ws + 16801792);        //  8,388,608  z-gate (live until scan_part3)
    u16*   wt     = (u16*)(ws + 25190400);        // 33,554,432  conv_w^T fused-tap (dead after conv)
    float* dlt    = (float*)(ws + 25190400);      // 16,777,216  delta (aliases wt, after conv)
    u16*   y_buf  = (u16*)(ws + 41967616);        //  8,388,608  (aliases wt)
    u16*   ssum   = (u16*)(ws + 50356224);        //  8,388,608  (aliases wt)
    u16*   inw    = (u16*)(ws + 58744832);        // 16,777,216  in_proj bf16 -> conv/out partial p0 (fp32 full) / dBC partials
    float* inwF   = (float*)(ws + 58744832);
    u16*   xpw    = (u16*)(ws + 75522048);        //    524,288
    float* dbc    = (float*)(ws + 76046336);      //    786,432
    u16*   dbc64  = (u16*)(ws + 76832768);        //    262,144
    u16*   dtw    = (u16*)(ws + 77094912);        //    131,072
    float* sdl    = (float*)(ws + 77225984);      //    524,288
    u16*   outw   = (u16*)(ws + 77750272);        //  8,388,608  conv partial p1b (fp32 half) -> out_proj bf16
    float* outwF  = (float*)(ws + 77750272);
    float* xcpF   = (float*)(ws);

    transpose_w<<<dim3(32, 32, 4), 256, 0, stream>>>(conv_w, wt);
    pad_zero_k<<<48, 256, 0, stream>>>(xcp);
    xpw_k<<<1024, 256, 0, stream>>>(x_proj, xpw);
    cast_f2b_k<<<8192, 256, 0, stream>>>(in_proj, inw);
    cast_f2b_k<<<128, 256, 0, stream>>>(dt_w, dtw);
    rmsnorm_k<<<2048, 256, 0, stream>>>(x, norm_w, hy);

    // xz = h @ in_proj_w.T : 256 blocks full chip, exact direct epilogue
    gemmA<EPI_XZ, false><<<dim3(16, 16, 1), 512, 0, stream>>>(
        hy, inw, 2048, 2048, 0, 0, 64, xcp, z_buf, nullptr, nullptr);

    // conv: fused-tap GEMM, K=8192 split z=2 (row-shift trick),
    // fp32 partials: z0 -> inwF (full), z1 -> hyF/outwF (m-split halves)
    gemmA<EPI_P2, true><<<dim3(16, 8, 2), 512, 0, stream>>>(
        xcp, wt, 2048, 4 * H, 4096, 4096, 128, inwF, hyF, outwF, nullptr);
    fin_conv2<<<4096, 256, 0, stream>>>(inwF, hyF, outwF, conv_b, (u16*)ws);

    cast_f2b_k<<<4096, 256, 0, stream>>>(out_w, outw);

    // dBC: 8-way K split, per-z fp32 partial stores, then fused sum
    gemm128d<EPI_STORE, false><<<dim3(1, 16, 8), 256, 0, stream>>>(
        (u16*)ws, xpw, 2048, 2048, 8, 256, 256, 262144, 128, inwF, nullptr, nullptr);
    fin_dbc_k<<<1024, 256, 0, stream>>>(inwF, dbc, dbc64);

    // delta = softplus(dbc64 @ dt_proj_w.T + dt_b)
    gemm_bt<EPI_DELTA, false><<<dim3(16, 16, 1), 256, 0, stream>>>(
        dbc64, dtw, 64, 0, 0, 2, 0, dlt, nullptr, dt_b);

    // chunked channel-per-thread scan (+ fused gate); xc = xcc in xcp region
    scan_part1<<<dim3(64, 8), 256, 0, stream>>>(dlt, (u16*)ws, dbc, a_log, ssum, sdl);
    scan_mid<<<256, 256, 0, stream>>>(ssum, sdl, a_log);
    scan_part3<<<dim3(64, 8), 256, 0, stream>>>(dlt, (u16*)ws, dbc, a_log, Dv, z_buf, ssum, y_buf);

    // out = x + yg @ out_proj_w.T : z=2 fp32 partials (inwF full; hyF/xcpF halves)
    gemmA<EPI_P2, false><<<dim3(16, 8, 2), 512, 0, stream>>>(
        y_buf, outw, 2048, 2048, 1024, 1024, 32, inwF, hyF, xcpF, nullptr);
    fin_out2<<<4096, 256, 0, stream>>>(inwF, hyF, xcpF, x, out);
}

// Round 8
// 437.257 us; speedup vs baseline: 1.1687x; 1.1687x over previous
//
#include <hip/hip_runtime.h>
#include <math.h>

typedef unsigned short u16;
typedef __bf16 bf16x8 __attribute__((ext_vector_type(8)));
typedef float f32x4 __attribute__((ext_vector_type(4)));
typedef unsigned short u16x8 __attribute__((ext_vector_type(8)));
typedef unsigned short u16x4 __attribute__((ext_vector_type(4)));

#define H 2048
#define LSEQ 1024
#define LP (LSEQ+3)
#define CL 32
#define NCH 32

__device__ __forceinline__ float bf2f(u16 u) {
    union { float f; unsigned int i; } x; x.i = ((unsigned int)u) << 16; return x.f;
}
__device__ __forceinline__ u16 f2bf(float f) {
    union { float f; unsigned int i; } x; x.f = f;
    unsigned int r = x.i + 0x7fffu + ((x.i >> 16) & 1u);
    return (u16)(r >> 16);
}

__device__ __forceinline__ void gload_lds16(const void* g, void* l) {
    __builtin_amdgcn_global_load_lds((const __attribute__((address_space(1))) void*)g,
                                     (__attribute__((address_space(3))) void*)l,
                                     16, 0, 0);
}

enum { EPI_XZ = 0, EPI_DELTA = 1, EPI_STORE = 5, EPI_P2 = 6, EPI_OUT = 7 };

// ------- 128x256 tile, 8-wave (4 N-quarters x 2 K-halves), K-step 64, 3-ring -------
// r1's proven wave geometry (wave tile 128x64, 12 ds_read : 32 MFMA) adapted so the
// block stays 128x256 (256 full-chip blocks for XZ/conv). Each wave computes its
// 32-wide k-half; pairs (w, w+4) sum via LDS at the end. 144 KB LDS (1 block/CU),
// depth-2 prefetch, counted s_waitcnt vmcnt(6) (6 loads/thread/stage).
// Rows are 64 bf16 (8x16B granules); swizzle slot = g ^ (row&7), staged via
// pre-swizzled global source so ds_read_b128 is bank-balanced. No atomics.
template<int EPI, bool APAD>
__launch_bounds__(512, 2)
__global__ void gemmB(const u16* __restrict__ A, const u16* __restrict__ B,
                      int lda, int ldb, long aZoff, long bZoff, int iters,
                      void* __restrict__ out0, void* __restrict__ out1,
                      void* __restrict__ out2, const float* __restrict__ aux) {
    __shared__ u16 SM[73728];   // A: 3 x 128x64 @ [0,24576); B: 3 x 256x64 @ [24576,73728)
    const int m0 = blockIdx.x * 128;
    const int n0 = blockIdx.y * 256;
    const int z  = blockIdx.z;
    const int tid = threadIdx.x;
    const int lane = tid & 63;
    const int w = tid >> 6;          // 0..7
    const int wc2 = w & 3;           // N quarter (64 cols)
    const int kh = w >> 2;           // K half (32 of each 64-step)

    long abase;
    if (APAD) {
        int b = m0 >> 10, l0 = m0 & 1023;
        abase = (long)(b * LP + l0) * lda;
    } else {
        abase = (long)m0 * lda;
    }
    const u16* Ag = A + abase + (long)z * aZoff;
    const u16* Bg = B + (long)n0 * ldb + (long)z * bZoff;

    // frag read slot: granule g = kh*4 + (lane>>4), row&7 = lane&7
    const int sw16 = (((kh << 2) + (lane >> 4)) ^ (lane & 7)) * 8;

    f32x4 acc[8][4];
#pragma unroll
    for (int i = 0; i < 8; i++)
#pragma unroll
        for (int j = 0; j < 4; j++) acc[i][j] = (f32x4){0.f, 0.f, 0.f, 0.f};

    // stage K64-step s into ring buffer bi: A 1024 granules (2/thr), B 2048 (4/thr)
#define STG(s, bi)                                                                   \
    {                                                                                \
        const int k0_ = (s) * 64;                                                    \
        _Pragma("unroll")                                                            \
        for (int l_ = 0; l_ < 2; l_++) {                                             \
            const int idx_ = l_ * 512 + tid;                                         \
            const int r_ = idx_ >> 3;                                                \
            const int gs_ = ((idx_ & 7) ^ (r_ & 7)) * 8;                             \
            gload_lds16(Ag + (long)r_ * lda + k0_ + gs_, &SM[(bi) * 8192 + idx_ * 8]); \
        }                                                                            \
        _Pragma("unroll")                                                            \
        for (int l_ = 0; l_ < 4; l_++) {                                             \
            const int idx_ = l_ * 512 + tid;                                         \
            const int r_ = idx_ >> 3;                                                \
            const int gs_ = ((idx_ & 7) ^ (r_ & 7)) * 8;                             \
            gload_lds16(Bg + (long)r_ * ldb + k0_ + gs_, &SM[24576 + (bi) * 16384 + idx_ * 8]); \
        }                                                                            \
    }

    STG(0, 0);
    if (iters > 1) {
        STG(1, 1);
        asm volatile("s_waitcnt vmcnt(6)" ::: "memory");
    } else {
        asm volatile("s_waitcnt vmcnt(0)" ::: "memory");
    }
    __builtin_amdgcn_s_barrier();
    __builtin_amdgcn_sched_barrier(0);

    int cur = 0;
    for (int t = 0; t < iters; ++t) {
        const int sb = cur ? cur - 1 : 2;         // ring buffer for stage t+2
        if (t + 2 < iters) STG(t + 2, sb);

        bf16x8 af[8], bfr[4];
#pragma unroll
        for (int i = 0; i < 8; i++)
            af[i] = *(const bf16x8*)&SM[cur * 8192 + (i * 16 + (lane & 15)) * 64 + sw16];
#pragma unroll
        for (int j = 0; j < 4; j++)
            bfr[j] = *(const bf16x8*)&SM[24576 + cur * 16384 + (wc2 * 64 + j * 16 + (lane & 15)) * 64 + sw16];
        __builtin_amdgcn_s_setprio(1);
#pragma unroll
        for (int i = 0; i < 8; i++)
#pragma unroll
            for (int j = 0; j < 4; j++)
                acc[i][j] = __builtin_amdgcn_mfma_f32_16x16x32_bf16(af[i], bfr[j], acc[i][j], 0, 0, 0);
        __builtin_amdgcn_s_setprio(0);

        if (t < iters - 1) {
            if (t + 2 < iters) asm volatile("s_waitcnt vmcnt(6)" ::: "memory");
            else               asm volatile("s_waitcnt vmcnt(0)" ::: "memory");
            __builtin_amdgcn_s_barrier();
            __builtin_amdgcn_sched_barrier(0);
        }
        cur = (cur == 2) ? 0 : cur + 1;
    }
#undef STG

    // cross-K-half reduction: waves kh=1 dump acc into LDS; kh=0 add and store.
    __syncthreads();
    float* red = (float*)SM;                      // 4 regions x 8192 floats = 128 KB
    const int rb = wc2 * 8192;
    if (kh) {
#pragma unroll
        for (int i = 0; i < 8; i++)
#pragma unroll
            for (int j = 0; j < 4; j++)
#pragma unroll
                for (int r = 0; r < 4; r++)
                    red[rb + ((i * 4 + j) * 4 + r) * 64 + lane] = acc[i][j][r];
    }
    __syncthreads();
    if (!kh) {
#pragma unroll
        for (int i = 0; i < 8; i++) {
#pragma unroll
            for (int j = 0; j < 4; j++) {
#pragma unroll
                for (int r = 0; r < 4; r++) {
                    float v = acc[i][j][r] + red[rb + ((i * 4 + j) * 4 + r) * 64 + lane];
                    const int m = m0 + i * 16 + ((lane >> 4) << 2) + r;
                    const int n = n0 + wc2 * 64 + j * 16 + (lane & 15);
                    if constexpr (EPI == EPI_XZ) {
                        const int b = m >> 10, l = m & 1023;
                        if (n < H) ((u16*)out0)[((long)(b * LP + l + 3)) * H + n] = f2bf(v);
                        else       ((u16*)out1)[(long)m * H + (n - H)] = f2bf(v);
                    } else if constexpr (EPI == EPI_OUT) {
                        ((float*)out0)[(long)m * H + n] = v + aux[(long)m * H + n];
                    } else {   // EPI_P2: fp32 split-K partial stores
                        if (z == 0) {
                            ((float*)out0)[(long)m * H + n] = v;
                        } else {
                            float* p = (m < 1024) ? (float*)out1 : (float*)out2;
                            p[(long)(m & 1023) * H + n] = v;
                        }
                    }
                }
            }
        }
    }
}

// ---------------- 128x128 tile GEMM, 2-barrier (DELTA only) ----------------
template<int EPI, bool APAD>
__launch_bounds__(256)
__global__ void gemm_bt(const u16* __restrict__ A, const u16* __restrict__ B,
                        int K, long aZoff, long bZoff, int itersZ, int ldc,
                        void* __restrict__ out0, void* __restrict__ out1,
                        const float* __restrict__ bias) {
    __shared__ u16 As[128 * 32];
    __shared__ u16 Bs[128 * 32];
    const int m0 = blockIdx.x * 128;
    const int n0 = blockIdx.y * 128;
    const int z  = blockIdx.z;
    const int tid = threadIdx.x;
    const int lane = tid & 63;
    const int w = tid >> 6;
    const int wr = w >> 1, wc = w & 1;

    long abase = (long)m0 * K;
    const u16* Ag = A + abase + (long)z * aZoff;
    const u16* Bg = B + (long)n0 * K + (long)z * bZoff;

    const int sw8 = ((((lane & 15) >> 1) & 3) ^ (lane >> 4)) * 8;

    f32x4 acc[4][4];
#pragma unroll
    for (int i = 0; i < 4; i++)
#pragma unroll
        for (int j = 0; j < 4; j++) acc[i][j] = (f32x4){0.f, 0.f, 0.f, 0.f};

    for (int kt = 0; kt < itersZ; ++kt) {
        const int k0 = kt * 32;
        __syncthreads();
#pragma unroll
        for (int j = 0; j < 2; j++) {
            const int idx = j * 256 + tid;
            const int r = idx >> 2;
            const int segG = ((idx & 3) ^ ((r >> 1) & 3)) * 8;
            gload_lds16(Ag + (long)r * K + k0 + segG, &As[idx * 8]);
            gload_lds16(Bg + (long)r * K + k0 + segG, &Bs[idx * 8]);
        }
        __syncthreads();
        bf16x8 af[4], bfr[4];
#pragma unroll
        for (int i = 0; i < 4; i++) {
            const int row = wr * 64 + i * 16 + (lane & 15);
            af[i] = *(const bf16x8*)&As[row * 32 + sw8];
        }
#pragma unroll
        for (int j = 0; j < 4; j++) {
            const int row = wc * 64 + j * 16 + (lane & 15);
            bfr[j] = *(const bf16x8*)&Bs[row * 32 + sw8];
        }
#pragma unroll
        for (int i = 0; i < 4; i++)
#pragma unroll
            for (int j = 0; j < 4; j++)
                acc[i][j] = __builtin_amdgcn_mfma_f32_16x16x32_bf16(af[i], bfr[j], acc[i][j], 0, 0, 0);
    }

#pragma unroll
    for (int i = 0; i < 4; i++) {
#pragma unroll
        for (int j = 0; j < 4; j++) {
#pragma unroll
            for (int r = 0; r < 4; r++) {
                const int m = m0 + wr * 64 + i * 16 + ((lane >> 4) << 2) + r;
                const int n = n0 + wc * 64 + j * 16 + (lane & 15);
                float v = acc[i][j][r];
                if constexpr (EPI == EPI_DELTA) {
                    v += bias[n];
                    v = (v > 20.f) ? v : log1pf(expf(v));   // softplus
                    ((float*)out0)[(long)m * H + n] = v;
                }
            }
        }
    }
}

// ---------------- 128x128 deep-pipelined GEMM (dBC only, proven) ----------
template<int EPI, bool APAD>
__launch_bounds__(256)
__global__ void gemm128d(const u16* __restrict__ A, const u16* __restrict__ B,
                         int lda, int ldb, int iters,
                         long aZoff, long bZoff, long oZoff, int ldo,
                         void* __restrict__ out0, void* __restrict__ out1,
                         const float* __restrict__ aux) {
    __shared__ u16 As[6][128 * 32];
    __shared__ u16 Bs[6][128 * 32];
    const int m0 = blockIdx.y * 128;
    const int n0 = blockIdx.x * 128;
    const int z  = blockIdx.z;
    const int tid = threadIdx.x;
    const int lane = tid & 63;
    const int w = tid >> 6;
    const int wr = w >> 1, wc = w & 1;

    long abase = (long)m0 * lda;
    const u16* Ag = A + abase + (long)z * aZoff;
    const u16* Bg = B + (long)n0 * ldb + (long)z * bZoff;

    const int sw8 = ((((lane & 15) >> 1) & 3) ^ (lane >> 4)) * 8;

    f32x4 acc[4][4];
#pragma unroll
    for (int i = 0; i < 4; i++)
#pragma unroll
        for (int j = 0; j < 4; j++) acc[i][j] = (f32x4){0.f, 0.f, 0.f, 0.f};

#define STG(s, bi)                                                                \
    {                                                                             \
        const int k0_ = (s) * 32;                                                 \
        _Pragma("unroll")                                                         \
        for (int l_ = 0; l_ < 2; l_++) {                                          \
            const int idx_ = l_ * 256 + tid;                                      \
            const int r_ = idx_ >> 2;                                            \
            const int segG_ = ((idx_ & 3) ^ ((r_ >> 1) & 3)) * 8;                 \
            gload_lds16(Ag + (long)r_ * lda + k0_ + segG_, &As[bi][idx_ * 8]);    \
            gload_lds16(Bg + (long)r_ * ldb + k0_ + segG_, &Bs[bi][idx_ * 8]);    \
        }                                                                         \
    }

    STG(0, 0);
    if (iters > 1) STG(1, 1);
    if (iters > 2) STG(2, 2);
    if (iters > 3) STG(3, 3);
    if (iters > 4) STG(4, 4);
    {
        const int pre = iters < 5 ? iters : 5;
        if      (pre == 5) asm volatile("s_waitcnt vmcnt(16)" ::: "memory");
        else if (pre == 4) asm volatile("s_waitcnt vmcnt(12)" ::: "memory");
        else if (pre == 3) asm volatile("s_waitcnt vmcnt(8)" ::: "memory");
        else if (pre == 2) asm volatile("s_waitcnt vmcnt(4)" ::: "memory");
        else               asm volatile("s_waitcnt vmcnt(0)" ::: "memory");
    }
    __builtin_amdgcn_s_barrier();
    __builtin_amdgcn_sched_barrier(0);

    int cur = 0;
    for (int t = 0; t < iters; ++t) {
        const int sb = cur ? cur - 1 : 5;
        if (t + 5 < iters) STG(t + 5, sb);

        bf16x8 af[4], bfr[4];
#pragma unroll
        for (int i = 0; i < 4; i++) {
            const int row = wr * 64 + i * 16 + (lane & 15);
            af[i] = *(const bf16x8*)&As[cur][row * 32 + sw8];
        }
#pragma unroll
        for (int j = 0; j < 4; j++) {
            const int row = wc * 64 + j * 16 + (lane & 15);
            bfr[j] = *(const bf16x8*)&Bs[cur][row * 32 + sw8];
        }
        __builtin_amdgcn_s_setprio(1);
#pragma unroll
        for (int i = 0; i < 4; i++)
#pragma unroll
            for (int j = 0; j < 4; j++)
                acc[i][j] = __builtin_amdgcn_mfma_f32_16x16x32_bf16(af[i], bfr[j], acc[i][j], 0, 0, 0);
        __builtin_amdgcn_s_setprio(0);

        if (t < iters - 1) {
            const int lastst = (t + 5 < iters - 1) ? t + 5 : iters - 1;
            const int ahead = lastst - (t + 1);
            if      (ahead >= 4) asm volatile("s_waitcnt vmcnt(16)" ::: "memory");
            else if (ahead == 3) asm volatile("s_waitcnt vmcnt(12)" ::: "memory");
            else if (ahead == 2) asm volatile("s_waitcnt vmcnt(8)" ::: "memory");
            else if (ahead == 1) asm volatile("s_waitcnt vmcnt(4)" ::: "memory");
            else                 asm volatile("s_waitcnt vmcnt(0)" ::: "memory");
            __builtin_amdgcn_s_barrier();
            __builtin_amdgcn_sched_barrier(0);
        }
        cur = (cur == 5) ? 0 : cur + 1;
    }
#undef STG

#pragma unroll
    for (int i = 0; i < 4; i++) {
#pragma unroll
        for (int j = 0; j < 4; j++) {
#pragma unroll
            for (int r = 0; r < 4; r++) {
                const int m = m0 + wr * 64 + i * 16 + ((lane >> 4) << 2) + r;
                const int n = n0 + wc * 64 + j * 16 + (lane & 15);
                float v = acc[i][j][r];
                if constexpr (EPI == EPI_STORE) {
                    ((float*)out0 + (long)z * oZoff)[(long)m * ldo + n] = v;
                }
            }
        }
    }
}

// conv finalize: sum fp32 partials (p0 full; p1 m-split) + bias + silu -> bf16 xcc
__global__ void fin_conv2(const float* __restrict__ p0, const float* __restrict__ p1a,
                          const float* __restrict__ p1b, const float* __restrict__ bias,
                          u16* __restrict__ xcc) {
    const long i = ((long)blockIdx.x * 256 + threadIdx.x) * 4;
    f32x4 a = *(const f32x4*)(p0 + i);
    const long half = (long)1024 * 2048;
    const float* p1 = (i < half) ? p1a : p1b;
    const long i1 = (i < half) ? i : i - half;
    f32x4 b = *(const f32x4*)(p1 + i1);
    const int n = (int)(i & 2047);
    f32x4 bv = *(const f32x4*)(bias + n);
    u16x4 o;
#pragma unroll
    for (int j = 0; j < 4; j++) {
        float t = a[j] + b[j] + bv[j];
        o[j] = f2bf(t / (1.f + expf(-t)));
    }
    *(u16x4*)(xcc + i) = o;
}

// dbc finalize: sum 8 fp32 partials (T x 128) -> dbc fp32 (T x 96) + dbc64 bf16 (T x 64)
__global__ void fin_dbc_k(const float* __restrict__ pacc, float* __restrict__ dbc,
                          u16* __restrict__ dbc64) {
    const int i = blockIdx.x * 256 + threadIdx.x;
    const int m = i >> 7, n = i & 127;
    float v = 0.f;
#pragma unroll
    for (int zz = 0; zz < 8; zz++) v += pacc[zz * 262144 + i];
    if (n < 96) dbc[m * 96 + n] = v;
    if (n < 64) dbc64[m * 64 + n] = f2bf(v);
}

// conv_w (tap,i,o) fp32 -> Wt (o, tap*H+i) bf16  (fused-tap layout, ldb = 4*H)
__global__ void transpose_w(const float* __restrict__ in, u16* __restrict__ out) {
    __shared__ u16 s[64][72];
    const int tap = blockIdx.z;
    const long base = (long)tap * H * H;
    const int i0 = blockIdx.x * 64, o0 = blockIdx.y * 64;
    const int r = threadIdx.x >> 3;
    const int c = (threadIdx.x & 7) * 8;
#pragma unroll
    for (int rr = r; rr < 64; rr += 32) {
        f32x4 a = *(const f32x4*)&in[base + (long)(i0 + rr) * H + o0 + c];
        f32x4 b = *(const f32x4*)&in[base + (long)(i0 + rr) * H + o0 + c + 4];
#pragma unroll
        for (int j = 0; j < 4; j++) { s[rr][c + j] = f2bf(a[j]); s[rr][c + 4 + j] = f2bf(b[j]); }
    }
    __syncthreads();
#pragma unroll
    for (int rr = r; rr < 64; rr += 32) {
        u16x8 v;
#pragma unroll
        for (int j = 0; j < 8; j++) v[j] = s[c + j][rr];
        *(u16x8*)&out[(long)(o0 + rr) * (4 * H) + (long)tap * H + i0 + c] = v;
    }
}

__global__ void cast_f2b_k(const float* __restrict__ in, u16* __restrict__ out) {
    const long i = ((long)blockIdx.x * 256 + threadIdx.x) * 4;
    f32x4 v = *(const f32x4*)(in + i);
    u16x4 o;
#pragma unroll
    for (int j = 0; j < 4; j++) o[j] = f2bf(v[j]);
    *(u16x4*)(out + i) = o;
}

__global__ void pad_zero_k(u16* __restrict__ xcp) {
    const int i = blockIdx.x * 256 + threadIdx.x;
    const int b = i / (3 * H);
    const int r = i - b * 3 * H;
    xcp[(long)b * LP * H + r] = 0;
}

__global__ void xpw_k(const float* __restrict__ xp, u16* __restrict__ out) {
    const int i = blockIdx.x * 256 + threadIdx.x;
    const int r = i >> 11;
    out[i] = (r < 96) ? f2bf(xp[i]) : (u16)0;
}

__global__ void rmsnorm_k(const float* __restrict__ x, const float* __restrict__ w, u16* __restrict__ h) {
    const long base = (long)blockIdx.x * H;
    const int tid = threadIdx.x;
    f32x4 a = *(const f32x4*)&x[base + tid * 8];
    f32x4 b = *(const f32x4*)&x[base + tid * 8 + 4];
    float f[8];
    float ss = 0.f;
#pragma unroll
    for (int j = 0; j < 4; j++) { f[j] = a[j]; f[4 + j] = b[j]; }
#pragma unroll
    for (int j = 0; j < 8; j++) ss += f[j] * f[j];
#pragma unroll
    for (int m = 32; m > 0; m >>= 1) ss += __shfl_down(ss, m);
    __shared__ float red[4];
    if ((tid & 63) == 0) red[tid >> 6] = ss;
    __syncthreads();
    ss = red[0] + red[1] + red[2] + red[3];
    const float scale = rsqrtf(ss * (1.f / H) + 1e-5f);
    f32x4 wa = *(const f32x4*)&w[tid * 8];
    f32x4 wb = *(const f32x4*)&w[tid * 8 + 4];
    u16x8 o;
#pragma unroll
    for (int j = 0; j < 4; j++) { o[j] = f2bf(f[j] * scale * wa[j]); o[4 + j] = f2bf(f[4 + j] * scale * wb[j]); }
    *(u16x8*)&h[base + tid * 8] = o;
}

// ---------- chunked scan, channel-per-thread ----------
__launch_bounds__(256)
__global__ void scan_part1(const float* __restrict__ delta, const u16* __restrict__ xc,
                           const float* __restrict__ dbc, const float* __restrict__ alog,
                           u16* __restrict__ ssum, float* __restrict__ sdl_buf) {
    __shared__ float sB[CL * 16];
    const int tid = threadIdx.x;
    const int bc = blockIdx.x;
    const int b = bc >> 5, c = bc & 31;
    const int h = blockIdx.y * 256 + tid;
    const long tok0 = (long)b * LSEQ + c * CL;
    {
        const int r = tid >> 4, n = tid & 15;
        sB[tid] = dbc[(tok0 + r) * 96 + 64 + n];
        sB[tid + 256] = dbc[(tok0 + r + 16) * 96 + 64 + n];
    }
    __syncthreads();
    float An[16]; bool fast = true;
#pragma unroll
    for (int n = 0; n < 16; n++) {
        An[n] = -expf(alog[h * 16 + n]);
        fast = fast && (fabsf(An[n] + (float)(n + 1)) < 1e-3f * (n + 1));
    }
    float s[16];
#pragma unroll
    for (int n = 0; n < 16; n++) s[n] = 0.f;
    float sdl = 0.f;
    const float* dptr = delta + tok0 * H + h;
    const u16* xptr = xc + tok0 * H + h;
    float dl = dptr[0], xv = bf2f(xptr[0]);
    if (fast) {
        for (int j = 0; j < CL; j++) {
            const long jn = (j < CL - 1) ? (long)(j + 1) * H : (long)j * H;
            const float dl2 = dptr[jn]; const float xv2 = bf2f(xptr[jn]);
            sdl += dl;
            const float e1 = expf(-dl);
            const float u = dl * xv;
            const f32x4* Bv = (const f32x4*)&sB[j * 16];
            float ep = 1.f;
#pragma unroll
            for (int q = 0; q < 4; q++) {
                const f32x4 bb = Bv[q];
#pragma unroll
                for (int k = 0; k < 4; k++) { ep *= e1; s[q*4+k] = ep * s[q*4+k] + u * bb[k]; }
            }
            dl = dl2; xv = xv2;
        }
    } else {
        for (int j = 0; j < CL; j++) {
            const long jn = (j < CL - 1) ? (long)(j + 1) * H : (long)j * H;
            const float dl2 = dptr[jn]; const float xv2 = bf2f(xptr[jn]);
            sdl += dl;
            const float u = dl * xv;
            const f32x4* Bv = (const f32x4*)&sB[j * 16];
#pragma unroll
            for (int q = 0; q < 4; q++) {
                const f32x4 bb = Bv[q];
#pragma unroll
                for (int k = 0; k < 4; k++) { const float e = expf(dl * An[q*4+k]); s[q*4+k] = e * s[q*4+k] + u * bb[k]; }
            }
            dl = dl2; xv = xv2;
        }
    }
    u16x8 o0, o1;
#pragma unroll
    for (int n = 0; n < 8; n++) { o0[n] = f2bf(s[n]); o1[n] = f2bf(s[8 + n]); }
    const long sb = ((long)bc * H + h) * 16;
    *(u16x8*)&ssum[sb] = o0;
    *(u16x8*)&ssum[sb + 8] = o1;
    sdl_buf[(long)bc * H + h] = sdl;
}

__global__ void scan_mid(u16* __restrict__ ssum, const float* __restrict__ sdl_buf,
                         const float* __restrict__ alog) {
    const int tg = blockIdx.x * 256 + threadIdx.x;
    const int b = tg >> 15;
    const int rest = tg & 32767;
    const int h = rest >> 4, n = rest & 15;
    const float An = -expf(alog[h * 16 + n]);
    float S = 0.f;
    for (int c = 0; c < NCH; c++) {
        const long base = (long)(b * NCH + c) * H + h;
        const float a = expf(An * sdl_buf[base]);
        const long si = base * 16 + n;
        const float sloc = bf2f(ssum[si]);
        ssum[si] = f2bf(S);
        S = a * S + sloc;
    }
}

__launch_bounds__(256)
__global__ void scan_part3(const float* __restrict__ delta, const u16* __restrict__ xc,
                           const float* __restrict__ dbc, const float* __restrict__ alog,
                           const float* __restrict__ dvec, const u16* __restrict__ z,
                           const u16* __restrict__ ssum, u16* __restrict__ ybuf) {
    __shared__ float sB[CL * 16];
    __shared__ float sC[CL * 16];
    const int tid = threadIdx.x;
    const int bc = blockIdx.x;
    const int b = bc >> 5, c = bc & 31;
    const int h = blockIdx.y * 256 + tid;
    const long tok0 = (long)b * LSEQ + c * CL;
    {
        const int r = tid >> 4, n = tid & 15;
        sB[tid]       = dbc[(tok0 + r) * 96 + 64 + n];
        sB[tid + 256] = dbc[(tok0 + r + 16) * 96 + 64 + n];
        sC[tid]       = dbc[(tok0 + r) * 96 + 80 + n];
        sC[tid + 256] = dbc[(tok0 + r + 16) * 96 + 80 + n];
    }
    __syncthreads();
    float An[16]; bool fast = true;
#pragma unroll
    for (int n = 0; n < 16; n++) {
        An[n] = -expf(alog[h * 16 + n]);
        fast = fast && (fabsf(An[n] + (float)(n + 1)) < 1e-3f * (n + 1));
    }
    float s[16];
    {
        const long sb = ((long)bc * H + h) * 16;
        u16x8 i0 = *(const u16x8*)&ssum[sb];
        u16x8 i1 = *(const u16x8*)&ssum[sb + 8];
#pragma unroll
        for (int n = 0; n < 8; n++) { s[n] = bf2f(i0[n]); s[8 + n] = bf2f(i1[n]); }
    }
    const float Dh = dvec[h];
    const float* dptr = delta + tok0 * H + h;
    const u16* xptr = xc + tok0 * H + h;
    const u16* zptr = z + tok0 * H + h;
    u16* yptr = ybuf + tok0 * H + h;
    float dl = dptr[0], xv = bf2f(xptr[0]), zf = bf2f(zptr[0]);
    if (fast) {
        for (int j = 0; j < CL; j++) {
            const long jn = (j < CL - 1) ? (long)(j + 1) * H : (long)j * H;
            const float dl2 = dptr[jn]; const float xv2 = bf2f(xptr[jn]); const float zf2 = bf2f(zptr[jn]);
            const float e1 = expf(-dl);
            const float u = dl * xv;
            const f32x4* Bv = (const f32x4*)&sB[j * 16];
            const f32x4* Cv = (const f32x4*)&sC[j * 16];
            float ep = 1.f, y = 0.f;
#pragma unroll
            for (int q = 0; q < 4; q++) {
                const f32x4 bb = Bv[q], cc = Cv[q];
#pragma unroll
                for (int k = 0; k < 4; k++) {
                    ep *= e1;
                    s[q*4+k] = ep * s[q*4+k] + u * bb[k];
                    y += s[q*4+k] * cc[k];
                }
            }
            y += Dh * xv;
            const float g = zf / (1.f + expf(-zf));
            yptr[(long)j * H] = f2bf(y * g);
            dl = dl2; xv = xv2; zf = zf2;
        }
    } else {
        for (int j = 0; j < CL; j++) {
            const long jn = (j < CL - 1) ? (long)(j + 1) * H : (long)j * H;
            const float dl2 = dptr[jn]; const float xv2 = bf2f(xptr[jn]); const float zf2 = bf2f(zptr[jn]);
            const float u = dl * xv;
            const f32x4* Bv = (const f32x4*)&sB[j * 16];
            const f32x4* Cv = (const f32x4*)&sC[j * 16];
            float y = 0.f;
#pragma unroll
            for (int q = 0; q < 4; q++) {
                const f32x4 bb = Bv[q], cc = Cv[q];
#pragma unroll
                for (int k = 0; k < 4; k++) {
                    const float e = expf(dl * An[q*4+k]);
                    s[q*4+k] = e * s[q*4+k] + u * bb[k];
                    y += s[q*4+k] * cc[k];
                }
            }
            y += Dh * xv;
            const float g = zf / (1.f + expf(-zf));
            yptr[(long)j * H] = f2bf(y * g);
            dl = dl2; xv = xv2; zf = zf2;
        }
    }
}

extern "C" void kernel_launch(void* const* d_in, const int* in_sizes, int n_in,
                              void* d_out, int out_size, void* d_ws, size_t ws_size,
                              hipStream_t stream) {
    const float* x       = (const float*)d_in[0];
    const float* norm_w  = (const float*)d_in[1];
    const float* in_proj = (const float*)d_in[2];
    const float* conv_w  = (const float*)d_in[3];
    const float* conv_b  = (const float*)d_in[4];
    const float* x_proj  = (const float*)d_in[5];
    const float* dt_w    = (const float*)d_in[6];
    const float* dt_b    = (const float*)d_in[7];
    const float* a_log   = (const float*)d_in[8];
    const float* Dv      = (const float*)d_in[9];
    const float* out_w   = (const float*)d_in[10];
    float* out = (float*)d_out;

    char* ws = (char*)d_ws;
    // region roles over time (total 86,138,880 bytes):
    u16*   xcp    = (u16*)(ws);                   //  8,413,184  XZ pad-xc -> conv A -> xcc
    u16*   hy     = (u16*)(ws + 8413184);         //  8,388,608  h -> conv partial p1a (fp32 half)
    float* hyF    = (float*)(ws + 8413184);
    u16*   z_buf  = (u16*)(ws + 16801792);        //  8,388,608  z-gate (live until scan_part3)
    u16*   wt     = (u16*)(ws + 25190400);        // 33,554,432  conv_w^T fused-tap (dead after conv)
    float* dlt    = (float*)(ws + 25190400);      // 16,777,216  delta (aliases wt, after conv)
    u16*   y_buf  = (u16*)(ws + 41967616);        //  8,388,608  (aliases wt)
    u16*   ssum   = (u16*)(ws + 50356224);        //  8,388,608  (aliases wt)
    u16*   inw    = (u16*)(ws + 58744832);        // 16,777,216  in_proj bf16 -> conv partial p0 / dBC partials
    float* inwF   = (float*)(ws + 58744832);
    u16*   xpw    = (u16*)(ws + 75522048);        //    524,288
    float* dbc    = (float*)(ws + 76046336);      //    786,432
    u16*   dbc64  = (u16*)(ws + 76832768);        //    262,144
    u16*   dtw    = (u16*)(ws + 77094912);        //    131,072
    float* sdl    = (float*)(ws + 77225984);      //    524,288
    u16*   outw   = (u16*)(ws + 77750272);        //  8,388,608  conv partial p1b (fp32 half) -> out_proj bf16
    float* outwF  = (float*)(ws + 77750272);

    transpose_w<<<dim3(32, 32, 4), 256, 0, stream>>>(conv_w, wt);
    pad_zero_k<<<48, 256, 0, stream>>>(xcp);
    xpw_k<<<1024, 256, 0, stream>>>(x_proj, xpw);
    cast_f2b_k<<<8192, 256, 0, stream>>>(in_proj, inw);
    cast_f2b_k<<<128, 256, 0, stream>>>(dt_w, dtw);
    rmsnorm_k<<<2048, 256, 0, stream>>>(x, norm_w, hy);

    // xz = h @ in_proj_w.T : 256 full-chip blocks, K=2048 (32 steps of 64), direct
    gemmB<EPI_XZ, false><<<dim3(16, 16, 1), 512, 0, stream>>>(
        hy, inw, 2048, 2048, 0, 0, 32, xcp, z_buf, nullptr, nullptr);

    // conv: fused-tap GEMM, K=8192 split z=2 (row-shift: aZoff = 2 rows),
    // fp32 partials: z0 -> inwF (full), z1 -> hyF/outwF (m-split halves)
    gemmB<EPI_P2, true><<<dim3(16, 8, 2), 512, 0, stream>>>(
        xcp, wt, 2048, 4 * H, 4096, 4096, 64, inwF, hyF, outwF, nullptr);
    fin_conv2<<<4096, 256, 0, stream>>>(inwF, hyF, outwF, conv_b, (u16*)ws);

    cast_f2b_k<<<4096, 256, 0, stream>>>(out_w, outw);

    // dBC: 8-way K split, per-z fp32 partial stores, then fused sum
    gemm128d<EPI_STORE, false><<<dim3(1, 16, 8), 256, 0, stream>>>(
        (u16*)ws, xpw, 2048, 2048, 8, 256, 256, 262144, 128, inwF, nullptr, nullptr);
    fin_dbc_k<<<1024, 256, 0, stream>>>(inwF, dbc, dbc64);

    // delta = softplus(dbc64 @ dt_proj_w.T + dt_b)
    gemm_bt<EPI_DELTA, false><<<dim3(16, 16, 1), 256, 0, stream>>>(
        dbc64, dtw, 64, 0, 0, 2, 0, dlt, nullptr, dt_b);

    // chunked channel-per-thread scan (+ fused gate); xc = xcc in xcp region
    scan_part1<<<dim3(64, 8), 256, 0, stream>>>(dlt, (u16*)ws, dbc, a_log, ssum, sdl);
    scan_mid<<<256, 256, 0, stream>>>(ssum, sdl, a_log);
    scan_part3<<<dim3(64, 8), 256, 0, stream>>>(dlt, (u16*)ws, dbc, a_log, Dv, z_buf, ssum, y_buf);

    // out = x + yg @ out_proj_w.T : K=2048 unsplit (32 steps), residual fused, direct
    gemmB<EPI_OUT, false><<<dim3(16, 8, 1), 512, 0, stream>>>(
        y_buf, outw, 2048, 2048, 0, 0, 32, out, nullptr, nullptr, x);
}